// Round 11
// baseline (169.494 us; speedup 1.0000x reference)
//
#include <hip/hip_runtime.h>
#include <hip/hip_bf16.h>

// ---------------------------------------------------------------------------
// FlashAttentionV2 on MI355X. bf16 MFMA throughout.
// R9/R10: flash P-transform eliminated — S^T C-layout == A-layout of K=16
// MFMA (v_mfma_f32_16x16x16_bf16) per 16-key slab, so P feeds PV straight
// from VGPRs (no ldsP, no lgkmcnt drain). V tile [d][key] with 8B XOR
// swizzle for conflict-free ds_read_b64 B-frags. LDS 40.5->32 KB.
// R10 fix: call __builtin_amdgcn_mfma_f32_16x16x16bf16_1k unconditionally
// (__has_builtin is false in the host pass and mis-fired #error).
// ---------------------------------------------------------------------------

typedef __attribute__((ext_vector_type(8))) short bf16x8;
typedef __attribute__((ext_vector_type(4))) short short4v;
typedef __attribute__((ext_vector_type(4))) float f32x4;

#define T_SEQ 2048
#define D_MODEL 1024
#define NHEAD 16
#define DHEAD 64
#define QK_SCALE 0.180336879f   // (1/8) * log2(e)

__device__ inline short f2bf(float f) {
    unsigned u = __float_as_uint(f);
    u += 0x7fffu + ((u >> 16) & 1u);   // RNE
    return (short)(u >> 16);
}

__device__ inline unsigned pk2(float a, float b) {
    __hip_bfloat162 h = __float22bfloat162_rn(make_float2(a, b));  // v_cvt_pk_bf16_f32
    return *(unsigned*)&h;
}

__device__ inline unsigned long long pk4(float a, float b, float c, float d) {
    return (unsigned long long)pk2(a, b) | ((unsigned long long)pk2(c, d) << 32);
}

__device__ inline f32x4 mfma16(bf16x8 a, bf16x8 b, f32x4 c) {
    return __builtin_amdgcn_mfma_f32_16x16x32_bf16(a, b, c, 0, 0, 0);
}

// K=16 bf16 MFMA (v_mfma_f32_16x16x16_bf16): A/B = 4 bf16 (2 VGPRs) per lane.
__device__ inline f32x4 mfma1616(short4v a, short4v b, f32x4 c) {
    return __builtin_amdgcn_mfma_f32_16x16x16bf16_1k(a, b, c, 0, 0, 0);
}

__device__ inline void gld_lds16(const short* g, short* l) {
    __builtin_amdgcn_global_load_lds(
        (const __attribute__((address_space(1))) void*)g,
        (__attribute__((address_space(3))) void*)l, 16, 0, 0);
}

// ---------------------------------------------------------------------------
// One dispatch: y=0 casts x (4M elems), y=1 casts the 4 weights.
// ---------------------------------------------------------------------------
__global__ __launch_bounds__(256) void cast_all(const float* __restrict__ x,
                                                const float* __restrict__ w0,
                                                const float* __restrict__ w1,
                                                const float* __restrict__ w2,
                                                const float* __restrict__ w3,
                                                short* __restrict__ xdst,
                                                short* __restrict__ wdst) {
    int i = (blockIdx.x * 256 + threadIdx.x) * 4;
    const float* s;
    short* d;
    if (blockIdx.y == 0) {
        s = x + i; d = xdst + i;
    } else {
        int m = i >> 20;
        s = ((m == 0) ? w0 : (m == 1) ? w1 : (m == 2) ? w2 : w3) + (i & 1048575);
        d = wdst + i;
    }
    float4 v = *(const float4*)s;
    short4v o = { f2bf(v.x), f2bf(v.y), f2bf(v.z), f2bf(v.w) };
    *(short4v*)d = o;
}

// ---------------------------------------------------------------------------
// Fused QKV GEMM: C = A[M,K] * B[N,K]^T, 128x128 tile, BK=32, swizzled LDS.
// Q output pre-scaled by QK_SCALE.
// ---------------------------------------------------------------------------
__global__ __launch_bounds__(256, 3) void gemm_qkv(const short* __restrict__ A,
                                                   const short* __restrict__ B,
                                                   short* __restrict__ C0,
                                                   short* __restrict__ C1,
                                                   short* __restrict__ C2,
                                                   int M, int N, int K) {
    __shared__ short As[4096];
    __shared__ short Bs[4096];

    const int tid = threadIdx.x;
    const int wave = tid >> 6, lane = tid & 63;
    const int g = lane >> 4, ln = lane & 15;
    const int mh = wave & 1, nh = wave >> 1;
    const int m_base = blockIdx.x * 128;
    const int n_base = blockIdx.y * 128;
    const int swz8 = 8 * (g ^ ((ln >> 1) & 3));

    const int srow = tid >> 2;
    const int scol = (((tid & 3) ^ ((tid >> 3) & 3))) * 8;
    const short* Ag = A + (long)(m_base + srow) * K + scol;
    const short* Bg = B + (long)(n_base + srow) * K + scol;
    const long r64 = 64 * (long)K;

    f32x4 acc[4][4];
#pragma unroll
    for (int i = 0; i < 4; i++)
#pragma unroll
        for (int j = 0; j < 4; j++) acc[i][j] = (f32x4){0.f, 0.f, 0.f, 0.f};

    for (int k0 = 0; k0 < K; k0 += 32) {
        gld_lds16(Ag + k0, As + tid * 8);
        gld_lds16(Ag + r64 + k0, As + 2048 + tid * 8);
        gld_lds16(Bg + k0, Bs + tid * 8);
        gld_lds16(Bg + r64 + k0, Bs + 2048 + tid * 8);
        __syncthreads();

        bf16x8 a[4], b[4];
#pragma unroll
        for (int mf = 0; mf < 4; mf++)
            a[mf] = *(const bf16x8*)(As + (mh * 64 + mf * 16 + ln) * 32 + swz8);
#pragma unroll
        for (int nf = 0; nf < 4; nf++)
            b[nf] = *(const bf16x8*)(Bs + (nh * 64 + nf * 16 + ln) * 32 + swz8);
#pragma unroll
        for (int mf = 0; mf < 4; mf++)
#pragma unroll
            for (int nf = 0; nf < 4; nf++)
                acc[mf][nf] = mfma16(a[mf], b[nf], acc[mf][nf]);
        __syncthreads();
    }

    const int mat = n_base >> 10;   // 0=Q, 1=K, 2=V (uniform per block)
    if (mat < 2) {
        short* dst = mat == 0 ? C0 : C1;
        const float scl = (mat == 0) ? QK_SCALE : 1.f;
#pragma unroll
        for (int mf = 0; mf < 4; mf++)
#pragma unroll
            for (int nf = 0; nf < 4; nf++)
#pragma unroll
                for (int r = 0; r < 4; r++) {
                    int row = m_base + mh * 64 + mf * 16 + g * 4 + r;
                    int cc = (n_base & 1023) + nh * 64 + nf * 16 + ln;
                    int b_ = row >> 11, t = row & 2047;
                    int h = cc >> 6, d = cc & 63;
                    dst[(((long)(b_ * NHEAD + h) * T_SEQ + t) << 6) + d] =
                        f2bf(acc[mf][nf][r] * scl);
                }
    } else {
        short* dst = C2;   // (B,H,dh,T): pack 4 bf16 along t
#pragma unroll
        for (int mf = 0; mf < 4; mf++)
#pragma unroll
            for (int nf = 0; nf < 4; nf++) {
                unsigned long long pk = pk4(acc[mf][nf][0], acc[mf][nf][1],
                                            acc[mf][nf][2], acc[mf][nf][3]);
                int cc = (n_base & 1023) + nh * 64 + nf * 16 + ln;
                int row0 = m_base + mh * 64 + mf * 16 + g * 4;
                int b_ = row0 >> 11, t = row0 & 2047;
                *(unsigned long long*)(&dst[((long)(b_ * 1024 + cc) << 11) + t]) = pk;
            }
    }
}

// ---------------------------------------------------------------------------
// Out-projection GEMM: fp32 C = A[M,K] * B[N,K]^T, 128x64 tile, swizzled LDS.
// ---------------------------------------------------------------------------
__global__ __launch_bounds__(256, 3) void gemm_out(const short* __restrict__ A,
                                                   const short* __restrict__ B,
                                                   float* __restrict__ C,
                                                   int M, int N, int K) {
    __shared__ short As[4096];
    __shared__ short Bs[2048];

    const int tid = threadIdx.x;
    const int wave = tid >> 6, lane = tid & 63;
    const int g = lane >> 4, ln = lane & 15;
    const int mh = wave & 1, nh = wave >> 1;
    const int m_base = blockIdx.x * 128;
    const int n_base = blockIdx.y * 64;
    const int swz8 = 8 * (g ^ ((ln >> 1) & 3));

    const int srow = tid >> 2;
    const int scol = (((tid & 3) ^ ((tid >> 3) & 3))) * 8;
    const short* Ag = A + (long)(m_base + srow) * K + scol;
    const short* Bg = B + (long)(n_base + srow) * K + scol;
    const long r64 = 64 * (long)K;

    f32x4 acc[4][2];
#pragma unroll
    for (int i = 0; i < 4; i++)
#pragma unroll
        for (int j = 0; j < 2; j++) acc[i][j] = (f32x4){0.f, 0.f, 0.f, 0.f};

    for (int k0 = 0; k0 < K; k0 += 32) {
        gld_lds16(Ag + k0, As + tid * 8);
        gld_lds16(Ag + r64 + k0, As + 2048 + tid * 8);
        gld_lds16(Bg + k0, Bs + tid * 8);
        __syncthreads();

        bf16x8 a[4], b[2];
#pragma unroll
        for (int mf = 0; mf < 4; mf++)
            a[mf] = *(const bf16x8*)(As + (mh * 64 + mf * 16 + ln) * 32 + swz8);
#pragma unroll
        for (int nf = 0; nf < 2; nf++)
            b[nf] = *(const bf16x8*)(Bs + (nh * 32 + nf * 16 + ln) * 32 + swz8);
#pragma unroll
        for (int mf = 0; mf < 4; mf++)
#pragma unroll
            for (int nf = 0; nf < 2; nf++)
                acc[mf][nf] = mfma16(a[mf], b[nf], acc[mf][nf]);
        __syncthreads();
    }

#pragma unroll
    for (int mf = 0; mf < 4; mf++)
#pragma unroll
        for (int nf = 0; nf < 2; nf++)
#pragma unroll
            for (int r = 0; r < 4; r++) {
                int row = m_base + mh * 64 + mf * 16 + g * 4 + r;
                int col = n_base + nh * 32 + nf * 16 + ln;
                C[(long)row * N + col] = acc[mf][nf][r];
            }
}

// ---------------------------------------------------------------------------
// Flash attention (causal), unnormalized softmax, transposed scores,
// register-direct P (K=16 PV MFMA). Grid 1024: qx=31-(id>>5) (LPT),
// bh=id&31 (XCD pin). 4 waves x 16 q-rows.
// K tile: [half dh][64 keys][32 shorts] (4-chunk XOR swizzle, as R6).
// V tile: [d 0..63][64 keys], 16B-pair slot = pair ^ ((d>>1)&7).
// ---------------------------------------------------------------------------
__global__ __launch_bounds__(256) void flash_attn(const short* __restrict__ Q,
                                                  const short* __restrict__ Kx,
                                                  const short* __restrict__ Vt,
                                                  short* __restrict__ O) {
    __shared__ short Ks[2][4096];
    __shared__ short Vs[2][4096];

    const int tid = threadIdx.x;
    const int wv = tid >> 6, lane = tid & 63;
    const int g = lane >> 4, ln = lane & 15;
    const int id = blockIdx.x;
    const int qx = 31 - (id >> 5);
    const int bh = id & 31;
    const int swz8 = 8 * (g ^ ((ln >> 1) & 3));

    const short* Kp = Kx + (long)bh * (T_SEQ * DHEAD);
    const short* Vp = Vt + (long)bh * (DHEAD * T_SEQ);

    // K staging map: row tid>>2, chunk (tid&3)^((tid>>3)&3)
    const int sr = tid >> 2;
    const int sc8 = (((tid & 3) ^ ((tid >> 3) & 3))) * 8;
    const int offK0 = sr * 64 + sc8;
    // V staging map: LDS 16B slot u = {tid, 256+tid}: d=u>>3, pair=(u&7)^((d>>1)&7)
    const int vd0 = tid >> 3, vd1 = (256 + tid) >> 3;
    const long offV0 = (long)vd0 * T_SEQ + 8 * ((tid & 7) ^ ((vd0 >> 1) & 7));
    const long offV1 = (long)vd1 * T_SEQ + 8 * ((tid & 7) ^ ((vd1 >> 1) & 7));
    const int ldst = tid * 8;

    const int nt = qx + 1;
    const int qrow0 = qx * 64 + wv * 16;

    const short* Qp = Q + ((long)bh * T_SEQ + qrow0) * DHEAD;
    bf16x8 qf0 = *(const bf16x8*)(Qp + ln * 64 + 8 * g);
    bf16x8 qf1 = *(const bf16x8*)(Qp + ln * 64 + 32 + 8 * g);

    f32x4 o[4];
#pragma unroll
    for (int nf = 0; nf < 4; nf++) o[nf] = (f32x4){0.f, 0.f, 0.f, 0.f};
    float li = 0.f;

    // pre-stage tile 0
    gld_lds16(Kp + offK0, &Ks[0][ldst]);
    gld_lds16(Kp + offK0 + 32, &Ks[0][2048 + ldst]);
    gld_lds16(Vp + offV0, &Vs[0][ldst]);
    gld_lds16(Vp + offV1, &Vs[0][2048 + ldst]);

    // V B-frag LDS offsets: d=nf*16+ln, pair=2j+(g>>1) swizzled by (ln>>1)&7,
    // beta=g&1 -> shorts: d*64 + 8*(pair^((ln>>1)&7)) + 4*beta
    int voff[4][4];
#pragma unroll
    for (int j = 0; j < 4; j++)
#pragma unroll
        for (int nf = 0; nf < 4; nf++)
            voff[j][nf] = (nf * 16 + ln) * 64 +
                          8 * ((2 * j + (g >> 1)) ^ ((ln >> 1) & 7)) + 4 * (g & 1);

    int buf = 0;
    for (int i = 0; i < nt; i++) {
        __syncthreads();
        if (i + 1 < nt) {
            const int kO = (i + 1) * 4096 + offK0;
            gld_lds16(Kp + kO, &Ks[buf ^ 1][ldst]);
            gld_lds16(Kp + kO + 32, &Ks[buf ^ 1][2048 + ldst]);
            gld_lds16(Vp + offV0 + (i + 1) * 64, &Vs[buf ^ 1][ldst]);
            gld_lds16(Vp + offV1 + (i + 1) * 64, &Vs[buf ^ 1][2048 + ldst]);
        }

        // S^T = K * Q^T (Q pre-scaled): s[j][r] = S[q=ln][key=16j+4g+r]*sc
        f32x4 s[4];
#pragma unroll
        for (int j = 0; j < 4; j++) {
            bf16x8 k0 = *(const bf16x8*)(&Ks[buf][(j * 16 + ln) * 32 + swz8]);
            bf16x8 k1 = *(const bf16x8*)(&Ks[buf][2048 + (j * 16 + ln) * 32 + swz8]);
            s[j] = mfma16(k0, qf0, (f32x4){0.f, 0.f, 0.f, 0.f});
            s[j] = mfma16(k1, qf1, s[j]);
        }

        // V B-frags (hoisted; independent of softmax)
        short4v vv[4][4];
#pragma unroll
        for (int j = 0; j < 4; j++)
#pragma unroll
            for (int nf = 0; nf < 4; nf++)
                vv[j][nf] = *(const short4v*)(&Vs[buf][voff[j][nf]]);

        if (i == nt - 1) {   // diagonal: mask key_local(16j+4g+r) > q_local(16wv+ln)
            const int ql = 16 * wv + ln;
#pragma unroll
            for (int j = 0; j < 4; j++) {
                int kl = 16 * j + 4 * g;
#pragma unroll
                for (int r = 0; r < 4; r++)
                    if (kl + r > ql) s[j][r] = -INFINITY;
            }
        }

        // exp2 -> pack -> PV directly from registers (C-layout == A-layout K=16)
#pragma unroll
        for (int j = 0; j < 4; j++) {
            float e0 = __builtin_amdgcn_exp2f(s[j][0]);
            float e1 = __builtin_amdgcn_exp2f(s[j][1]);
            float e2 = __builtin_amdgcn_exp2f(s[j][2]);
            float e3 = __builtin_amdgcn_exp2f(s[j][3]);
            li += (e0 + e1) + (e2 + e3);
            unsigned long long p = pk4(e0, e1, e2, e3);
            short4v pa = *(short4v*)&p;
#pragma unroll
            for (int nf = 0; nf < 4; nf++)
                o[nf] = mfma1616(pa, vv[j][nf], o[nf]);
        }
        buf ^= 1;
    }

    li += __shfl_xor(li, 16);
    li += __shfl_xor(li, 32);

    float lr[4];
#pragma unroll
    for (int r = 0; r < 4; r++)
        lr[r] = 1.f / (__shfl(li, 4 * g + r) + 1e-9f);

    const int b = bh >> 4, h = bh & 15;
#pragma unroll
    for (int nf = 0; nf < 4; nf++) {
#pragma unroll
        for (int r = 0; r < 4; r++) {
            int rr = qrow0 + g * 4 + r;
            O[((long)(b * T_SEQ + rr) << 10) + h * 64 + nf * 16 + ln] =
                f2bf(o[nf][r] * lr[r]);
        }
    }
}

// ---------------------------------------------------------------------------
extern "C" void kernel_launch(void* const* d_in, const int* in_sizes, int n_in,
                              void* d_out, int out_size, void* d_ws, size_t ws_size,
                              hipStream_t stream) {
    const float* x  = (const float*)d_in[0];
    const float* Wq = (const float*)d_in[1];
    const float* Wk = (const float*)d_in[2];
    const float* Wv = (const float*)d_in[3];
    const float* Wo = (const float*)d_in[4];

    char* ws = (char*)d_ws;
    short* xb  = (short*)(ws + (0ull  << 20));
    short* wqb = (short*)(ws + (8ull  << 20));   // wq,wk,wv,wo contiguous 2MB each
    short* wob = (short*)(ws + (14ull << 20));
    short* Qb  = (short*)(ws + (16ull << 20));   // (B,H,T,64), pre-scaled
    short* Kb  = (short*)(ws + (24ull << 20));   // (B,H,T,64)
    short* Vtb = (short*)(ws + (32ull << 20));   // (B,H,64,T)
    short* Ab  = (short*)(ws + (40ull << 20));   // (B,T,1024)

    cast_all<<<dim3(4096, 2), 256, 0, stream>>>(x, Wq, Wk, Wv, Wo, xb, wqb);

    gemm_qkv<<<dim3(32, 24), 256, 0, stream>>>(xb, wqb, Qb, Kb, Vtb,
                                               4096, 3072, 1024);

    flash_attn<<<1024, 256, 0, stream>>>(Qb, Kb, Vtb, Ab);

    gemm_out<<<dim3(32, 16), 256, 0, stream>>>(Ab, wob, (float*)d_out,
                                               4096, 1024, 1024);
}